// Round 1
// baseline (1506.035 us; speedup 1.0000x reference)
//
#include <hip/hip_runtime.h>
#include <hip/hip_bf16.h>

#define N_NODES 100000
#define N_EDGES 3200000
#define N_GRAPHS 256
#define D_IN 320
#define D_H 64
#define SCAN_B 256

// ---------------- CSR build ----------------

__global__ void k_count(const int* __restrict__ dst, int* __restrict__ cnt) {
    int e = blockIdx.x * blockDim.x + threadIdx.x;
    if (e < N_EDGES) atomicAdd(&cnt[dst[e]], 1);
}

__global__ void k_dinv(const int* __restrict__ cnt, float* __restrict__ dinv) {
    int i = blockIdx.x * blockDim.x + threadIdx.x;
    if (i < N_NODES) {
        float deg = (float)(cnt[i] + 1);   // +1 self loop
        dinv[i] = 1.0f / sqrtf(deg);
    }
}

__global__ void k_scan1(const int* __restrict__ cnt, int* __restrict__ rowptr,
                        int* __restrict__ bsum) {
    __shared__ int tmp[SCAN_B];
    int idx = blockIdx.x * SCAN_B + threadIdx.x;
    int v = (idx < N_NODES) ? cnt[idx] : 0;
    tmp[threadIdx.x] = v;
    __syncthreads();
    for (int off = 1; off < SCAN_B; off <<= 1) {
        int t = (threadIdx.x >= off) ? tmp[threadIdx.x - off] : 0;
        __syncthreads();
        tmp[threadIdx.x] += t;
        __syncthreads();
    }
    if (idx < N_NODES) rowptr[idx] = tmp[threadIdx.x] - v;   // exclusive
    if (threadIdx.x == SCAN_B - 1) bsum[blockIdx.x] = tmp[threadIdx.x];
}

__global__ void k_scan2(int* __restrict__ bsum, int* __restrict__ rowptr, int nb) {
    __shared__ int tmp[512];
    int v = (threadIdx.x < nb) ? bsum[threadIdx.x] : 0;
    tmp[threadIdx.x] = v;
    __syncthreads();
    for (int off = 1; off < 512; off <<= 1) {
        int t = (threadIdx.x >= off) ? tmp[threadIdx.x - off] : 0;
        __syncthreads();
        tmp[threadIdx.x] += t;
        __syncthreads();
    }
    if (threadIdx.x < nb) bsum[threadIdx.x] = tmp[threadIdx.x] - v;  // exclusive
    if (threadIdx.x == 511) rowptr[N_NODES] = tmp[511];              // total = E
}

__global__ void k_scan3(int* __restrict__ rowptr, const int* __restrict__ bsum) {
    int idx = blockIdx.x * SCAN_B + threadIdx.x;
    if (idx < N_NODES) rowptr[idx] += bsum[blockIdx.x];
}

__global__ void k_fill(const int* __restrict__ src, const int* __restrict__ dst,
                       const int* __restrict__ rowptr, int* __restrict__ cursor,
                       int* __restrict__ col) {
    int e = blockIdx.x * blockDim.x + threadIdx.x;
    if (e < N_EDGES) {
        int d = dst[e];
        int pos = atomicAdd(&cursor[d], 1);
        col[rowptr[d] + pos] = src[e];
    }
}

// ---------------- layer kernels ----------------

// u[i] = (x[i,:] @ W) * dinv[i]   (320 -> 64). One wave per node, lane = out feature.
__global__ __launch_bounds__(256) void k_xform1(const float* __restrict__ x,
                                                const float* __restrict__ W,
                                                const float* __restrict__ dinv,
                                                float* __restrict__ u) {
    __shared__ float xs[4][D_IN];
    int wid = threadIdx.x >> 6;
    int lane = threadIdx.x & 63;
    int node = blockIdx.x * 4 + wid;
    if (node >= N_NODES) return;
    const float4* xr4 = (const float4*)(x + (size_t)node * D_IN);
    float4* xs4 = (float4*)xs[wid];
    xs4[lane] = xr4[lane];                       // 64 * 16B = 256 floats
    if (lane < 16) xs4[64 + lane] = xr4[64 + lane];  // remaining 64 floats
    float acc = 0.0f;
#pragma unroll 8
    for (int k = 0; k < D_IN; ++k)
        acc = fmaf(xs[wid][k], W[k * D_H + lane], acc);
    u[(size_t)node * D_H + lane] = acc * dinv[node];
}

// u[i] = (h[i,:] @ W) * dinv[i]   (64 -> 64). One wave per node.
__global__ __launch_bounds__(256) void k_xform(const float* __restrict__ h,
                                               const float* __restrict__ W,
                                               const float* __restrict__ dinv,
                                               float* __restrict__ u) {
    int lane = threadIdx.x & 63;
    int node = (blockIdx.x * blockDim.x + threadIdx.x) >> 6;
    if (node >= N_NODES) return;
    float hv = h[(size_t)node * D_H + lane];
    float acc = 0.0f;
#pragma unroll
    for (int k = 0; k < D_H; ++k)
        acc = fmaf(__shfl(hv, k, 64), W[k * D_H + lane], acc);
    u[(size_t)node * D_H + lane] = acc * dinv[node];
}

// h[i] = act( dinv[i] * (sum_{src in N(i)} u[src] + u[i]) + b )
__global__ __launch_bounds__(256) void k_agg(const float* __restrict__ u,
                                             const int* __restrict__ rowptr,
                                             const int* __restrict__ col,
                                             const float* __restrict__ dinv,
                                             const float* __restrict__ b,
                                             float* __restrict__ h, int relu) {
    int lane = threadIdx.x & 63;
    int node = (blockIdx.x * blockDim.x + threadIdx.x) >> 6;
    if (node >= N_NODES) return;
    int beg = rowptr[node], end = rowptr[node + 1];
    float acc = u[(size_t)node * D_H + lane];    // self loop
    int e = beg;
    for (; e + 3 < end; e += 4) {                // 4 independent gathers in flight
        int s0 = col[e], s1 = col[e + 1], s2 = col[e + 2], s3 = col[e + 3];
        float v0 = u[(size_t)s0 * D_H + lane];
        float v1 = u[(size_t)s1 * D_H + lane];
        float v2 = u[(size_t)s2 * D_H + lane];
        float v3 = u[(size_t)s3 * D_H + lane];
        acc += v0 + v1 + v2 + v3;
    }
    for (; e < end; ++e) acc += u[(size_t)col[e] * D_H + lane];
    acc = acc * dinv[node] + b[lane];
    if (relu) acc = fmaxf(acc, 0.0f);
    h[(size_t)node * D_H + lane] = acc;
}

// per-node dot with Wl, segment-sum by batch id
__global__ __launch_bounds__(256) void k_pool(const float* __restrict__ h,
                                              const int* __restrict__ batch,
                                              const float* __restrict__ Wl,
                                              float* __restrict__ gsum,
                                              int* __restrict__ gcnt) {
    int lane = threadIdx.x & 63;
    int node = (blockIdx.x * blockDim.x + threadIdx.x) >> 6;
    if (node >= N_NODES) return;
    float v = h[(size_t)node * D_H + lane] * Wl[lane];
#pragma unroll
    for (int m = 32; m > 0; m >>= 1) v += __shfl_xor(v, m, 64);
    if (lane == 0) {
        int g = batch[node];
        atomicAdd(&gsum[g], v);
        atomicAdd(&gcnt[g], 1);
    }
}

__global__ void k_final(const float* __restrict__ gsum, const int* __restrict__ gcnt,
                        const float* __restrict__ bl, float* __restrict__ out) {
    int g = threadIdx.x;
    if (g < N_GRAPHS) out[g] = gsum[g] / fmaxf((float)gcnt[g], 1.0f) + bl[0];
}

// ---------------- launch ----------------

extern "C" void kernel_launch(void* const* d_in, const int* in_sizes, int n_in,
                              void* d_out, int out_size, void* d_ws, size_t ws_size,
                              hipStream_t stream) {
    const float* x   = (const float*)d_in[0];
    const int*   ei  = (const int*)d_in[1];
    const int*   bat = (const int*)d_in[2];
    const float* W1  = (const float*)d_in[3];
    const float* b1  = (const float*)d_in[4];
    const float* W2  = (const float*)d_in[5];
    const float* b2  = (const float*)d_in[6];
    const float* W3  = (const float*)d_in[7];
    const float* b3  = (const float*)d_in[8];
    const float* Wl  = (const float*)d_in[9];
    const float* bl  = (const float*)d_in[10];
    float* out = (float*)d_out;

    char* p = (char*)d_ws;
    auto alloc = [&](size_t bytes) -> void* {
        void* r = (void*)p;
        p += (bytes + 255) & ~(size_t)255;
        return r;
    };
    int*   cnt    = (int*)alloc((size_t)N_NODES * 4);
    int*   rowptr = (int*)alloc((size_t)(N_NODES + 1) * 4);
    int*   cursor = (int*)alloc((size_t)N_NODES * 4);
    float* dinv   = (float*)alloc((size_t)N_NODES * 4);
    int*   colb   = (int*)alloc((size_t)N_EDGES * 4);
    int*   bsum   = (int*)alloc((size_t)512 * 4);
    float* u      = (float*)alloc((size_t)N_NODES * D_H * 4);
    float* h      = (float*)alloc((size_t)N_NODES * D_H * 4);
    float* gsum   = (float*)alloc((size_t)N_GRAPHS * 4);
    int*   gcnt   = (int*)alloc((size_t)N_GRAPHS * 4);

    hipMemsetAsync(cnt, 0, (size_t)N_NODES * 4, stream);
    hipMemsetAsync(cursor, 0, (size_t)N_NODES * 4, stream);
    hipMemsetAsync(gsum, 0, (size_t)N_GRAPHS * 4, stream);
    hipMemsetAsync(gcnt, 0, (size_t)N_GRAPHS * 4, stream);

    const int* srcp = ei;
    const int* dstp = ei + N_EDGES;

    int ebl = (N_EDGES + 255) / 256;
    int nbl = (N_NODES + 255) / 256;
    int nb  = (N_NODES + SCAN_B - 1) / SCAN_B;      // 391
    int wbl = (N_NODES * 64 + 255) / 256;           // one wave per node

    k_count<<<ebl, 256, 0, stream>>>(dstp, cnt);
    k_dinv<<<nbl, 256, 0, stream>>>(cnt, dinv);
    k_scan1<<<nb, SCAN_B, 0, stream>>>(cnt, rowptr, bsum);
    k_scan2<<<1, 512, 0, stream>>>(bsum, rowptr, nb);
    k_scan3<<<nb, SCAN_B, 0, stream>>>(rowptr, bsum);
    k_fill<<<ebl, 256, 0, stream>>>(srcp, dstp, rowptr, cursor, colb);

    // layer 1: 320 -> 64
    k_xform1<<<(N_NODES + 3) / 4, 256, 0, stream>>>(x, W1, dinv, u);
    k_agg<<<wbl, 256, 0, stream>>>(u, rowptr, colb, dinv, b1, h, 1);
    // layer 2: 64 -> 64
    k_xform<<<wbl, 256, 0, stream>>>(h, W2, dinv, u);
    k_agg<<<wbl, 256, 0, stream>>>(u, rowptr, colb, dinv, b2, h, 1);
    // layer 3: 64 -> 64
    k_xform<<<wbl, 256, 0, stream>>>(h, W3, dinv, u);
    k_agg<<<wbl, 256, 0, stream>>>(u, rowptr, colb, dinv, b3, h, 0);

    // pooling + head
    k_pool<<<wbl, 256, 0, stream>>>(h, bat, Wl, gsum, gcnt);
    k_final<<<1, 256, 0, stream>>>(gsum, gcnt, bl, out);
}

// Round 2
// 1071.195 us; speedup vs baseline: 1.4059x; 1.4059x over previous
//
#include <hip/hip_runtime.h>
#include <hip/hip_bf16.h>

#define N_NODES 100000
#define N_EDGES 3200000
#define N_GRAPHS 256
#define D_IN 320
#define D_H 64
#define SCAN_B 256

// ---------------- CSR build ----------------

__global__ void k_count(const int* __restrict__ dst, int* __restrict__ cnt) {
    int e = blockIdx.x * blockDim.x + threadIdx.x;
    if (e < N_EDGES) atomicAdd(&cnt[dst[e]], 1);
}

__global__ void k_dinv(const int* __restrict__ cnt, float* __restrict__ dinv) {
    int i = blockIdx.x * blockDim.x + threadIdx.x;
    if (i < N_NODES) {
        float deg = (float)(cnt[i] + 1);   // +1 self loop
        dinv[i] = 1.0f / sqrtf(deg);
    }
}

__global__ void k_scan1(const int* __restrict__ cnt, int* __restrict__ rowptr,
                        int* __restrict__ bsum) {
    __shared__ int tmp[SCAN_B];
    int idx = blockIdx.x * SCAN_B + threadIdx.x;
    int v = (idx < N_NODES) ? cnt[idx] : 0;
    tmp[threadIdx.x] = v;
    __syncthreads();
    for (int off = 1; off < SCAN_B; off <<= 1) {
        int t = (threadIdx.x >= off) ? tmp[threadIdx.x - off] : 0;
        __syncthreads();
        tmp[threadIdx.x] += t;
        __syncthreads();
    }
    if (idx < N_NODES) rowptr[idx] = tmp[threadIdx.x] - v;   // exclusive
    if (threadIdx.x == SCAN_B - 1) bsum[blockIdx.x] = tmp[threadIdx.x];
}

__global__ void k_scan2(int* __restrict__ bsum, int* __restrict__ rowptr, int nb) {
    __shared__ int tmp[512];
    int v = (threadIdx.x < nb) ? bsum[threadIdx.x] : 0;
    tmp[threadIdx.x] = v;
    __syncthreads();
    for (int off = 1; off < 512; off <<= 1) {
        int t = (threadIdx.x >= off) ? tmp[threadIdx.x - off] : 0;
        __syncthreads();
        tmp[threadIdx.x] += t;
        __syncthreads();
    }
    if (threadIdx.x < nb) bsum[threadIdx.x] = tmp[threadIdx.x] - v;  // exclusive
    if (threadIdx.x == 511) rowptr[N_NODES] = tmp[511];              // total = E
}

__global__ void k_scan3(int* __restrict__ rowptr, const int* __restrict__ bsum) {
    int idx = blockIdx.x * SCAN_B + threadIdx.x;
    if (idx < N_NODES) rowptr[idx] += bsum[blockIdx.x];
}

__global__ void k_fill(const int* __restrict__ src, const int* __restrict__ dst,
                       const int* __restrict__ rowptr, int* __restrict__ cursor,
                       int* __restrict__ col) {
    int e = blockIdx.x * blockDim.x + threadIdx.x;
    if (e < N_EDGES) {
        int d = dst[e];
        int pos = atomicAdd(&cursor[d], 1);
        col[rowptr[d] + pos] = src[e];
    }
}

// ---------------- layer kernels ----------------

// u[i] = (x[i,:] @ W) * dinv[i]   (320 -> 64). One wave per node, lane = out feature.
__global__ __launch_bounds__(256) void k_xform1(const float* __restrict__ x,
                                                const float* __restrict__ W,
                                                const float* __restrict__ dinv,
                                                float* __restrict__ u) {
    __shared__ float xs[4][D_IN];
    int wid = threadIdx.x >> 6;
    int lane = threadIdx.x & 63;
    int node = blockIdx.x * 4 + wid;
    if (node >= N_NODES) return;
    const float4* xr4 = (const float4*)(x + (size_t)node * D_IN);
    float4* xs4 = (float4*)xs[wid];
    xs4[lane] = xr4[lane];                       // 64 * 16B = 256 floats
    if (lane < 16) xs4[64 + lane] = xr4[64 + lane];  // remaining 64 floats
    float acc = 0.0f;
#pragma unroll 8
    for (int k = 0; k < D_IN; ++k)
        acc = fmaf(xs[wid][k], W[k * D_H + lane], acc);
    u[(size_t)node * D_H + lane] = acc * dinv[node];
}

// u[i] = (h[i,:] @ W) * dinv[i]   (64 -> 64). One wave per node.
__global__ __launch_bounds__(256) void k_xform(const float* __restrict__ h,
                                               const float* __restrict__ W,
                                               const float* __restrict__ dinv,
                                               float* __restrict__ u) {
    int lane = threadIdx.x & 63;
    int node = (blockIdx.x * blockDim.x + threadIdx.x) >> 6;
    if (node >= N_NODES) return;
    float hv = h[(size_t)node * D_H + lane];
    float acc = 0.0f;
#pragma unroll
    for (int k = 0; k < D_H; ++k)
        acc = fmaf(__shfl(hv, k, 64), W[k * D_H + lane], acc);
    u[(size_t)node * D_H + lane] = acc * dinv[node];
}

// gather-accumulate body shared by k_agg / k_agg_dot
__device__ __forceinline__ float agg_gather(const float* __restrict__ u,
                                            const int* __restrict__ col,
                                            int beg, int end, int lane, float acc) {
    int e = beg;
    for (; e + 7 < end; e += 8) {                // 8 independent gathers in flight
        int s0 = col[e],     s1 = col[e + 1], s2 = col[e + 2], s3 = col[e + 3];
        int s4 = col[e + 4], s5 = col[e + 5], s6 = col[e + 6], s7 = col[e + 7];
        float v0 = u[(size_t)s0 * D_H + lane];
        float v1 = u[(size_t)s1 * D_H + lane];
        float v2 = u[(size_t)s2 * D_H + lane];
        float v3 = u[(size_t)s3 * D_H + lane];
        float v4 = u[(size_t)s4 * D_H + lane];
        float v5 = u[(size_t)s5 * D_H + lane];
        float v6 = u[(size_t)s6 * D_H + lane];
        float v7 = u[(size_t)s7 * D_H + lane];
        acc += ((v0 + v1) + (v2 + v3)) + ((v4 + v5) + (v6 + v7));
    }
    for (; e < end; ++e) acc += u[(size_t)col[e] * D_H + lane];
    return acc;
}

// h[i] = relu( dinv[i] * (sum_{src in N(i)} u[src] + u[i]) + b )
__global__ __launch_bounds__(256) void k_agg(const float* __restrict__ u,
                                             const int* __restrict__ rowptr,
                                             const int* __restrict__ col,
                                             const float* __restrict__ dinv,
                                             const float* __restrict__ b,
                                             float* __restrict__ h) {
    int lane = threadIdx.x & 63;
    int node = (blockIdx.x * blockDim.x + threadIdx.x) >> 6;
    if (node >= N_NODES) return;
    float acc = u[(size_t)node * D_H + lane];    // self loop
    acc = agg_gather(u, col, rowptr[node], rowptr[node + 1], lane, acc);
    acc = acc * dinv[node] + b[lane];
    h[(size_t)node * D_H + lane] = fmaxf(acc, 0.0f);
}

// layer 3 fused with the linear head: val[i] = dot(agg_row + b3, Wl)
__global__ __launch_bounds__(256) void k_agg_dot(const float* __restrict__ u,
                                                 const int* __restrict__ rowptr,
                                                 const int* __restrict__ col,
                                                 const float* __restrict__ dinv,
                                                 const float* __restrict__ b,
                                                 const float* __restrict__ Wl,
                                                 float* __restrict__ val) {
    int lane = threadIdx.x & 63;
    int node = (blockIdx.x * blockDim.x + threadIdx.x) >> 6;
    if (node >= N_NODES) return;
    float acc = u[(size_t)node * D_H + lane];    // self loop
    acc = agg_gather(u, col, rowptr[node], rowptr[node + 1], lane, acc);
    acc = acc * dinv[node] + b[lane];
    float v = acc * Wl[lane];
#pragma unroll
    for (int m = 32; m > 0; m >>= 1) v += __shfl_xor(v, m, 64);
    if (lane == 0) val[node] = v;
}

// one block per graph: batch is sorted, binary-search the segment, reduce.
__global__ __launch_bounds__(256) void k_gpool(const float* __restrict__ val,
                                               const int* __restrict__ batch,
                                               const float* __restrict__ bl,
                                               float* __restrict__ out) {
    int g = blockIdx.x;
    int l = 0, r = N_NODES;                      // lower_bound(batch, g)
    while (l < r) { int m = (l + r) >> 1; if (batch[m] < g) l = m + 1; else r = m; }
    int lo = l;
    r = N_NODES;                                 // lower_bound(batch, g+1)
    while (l < r) { int m = (l + r) >> 1; if (batch[m] < g + 1) l = m + 1; else r = m; }
    int hi = l;
    float s = 0.0f;
    for (int i = lo + threadIdx.x; i < hi; i += 256) s += val[i];
#pragma unroll
    for (int m = 32; m > 0; m >>= 1) s += __shfl_xor(s, m, 64);
    __shared__ float red[4];
    int wid = threadIdx.x >> 6, lane = threadIdx.x & 63;
    if (lane == 0) red[wid] = s;
    __syncthreads();
    if (threadIdx.x == 0) {
        float t = red[0] + red[1] + red[2] + red[3];
        out[g] = t / fmaxf((float)(hi - lo), 1.0f) + bl[0];
    }
}

// ---------------- launch ----------------

extern "C" void kernel_launch(void* const* d_in, const int* in_sizes, int n_in,
                              void* d_out, int out_size, void* d_ws, size_t ws_size,
                              hipStream_t stream) {
    const float* x   = (const float*)d_in[0];
    const int*   ei  = (const int*)d_in[1];
    const int*   bat = (const int*)d_in[2];
    const float* W1  = (const float*)d_in[3];
    const float* b1  = (const float*)d_in[4];
    const float* W2  = (const float*)d_in[5];
    const float* b2  = (const float*)d_in[6];
    const float* W3  = (const float*)d_in[7];
    const float* b3  = (const float*)d_in[8];
    const float* Wl  = (const float*)d_in[9];
    const float* bl  = (const float*)d_in[10];
    float* out = (float*)d_out;

    char* p = (char*)d_ws;
    auto alloc = [&](size_t bytes) -> void* {
        void* r = (void*)p;
        p += (bytes + 255) & ~(size_t)255;
        return r;
    };
    int*   cnt    = (int*)alloc((size_t)N_NODES * 4);
    int*   rowptr = (int*)alloc((size_t)(N_NODES + 1) * 4);
    int*   cursor = (int*)alloc((size_t)N_NODES * 4);
    float* dinv   = (float*)alloc((size_t)N_NODES * 4);
    int*   colb   = (int*)alloc((size_t)N_EDGES * 4);
    int*   bsum   = (int*)alloc((size_t)512 * 4);
    float* u      = (float*)alloc((size_t)N_NODES * D_H * 4);
    float* h      = (float*)alloc((size_t)N_NODES * D_H * 4);
    float* val    = (float*)alloc((size_t)N_NODES * 4);

    hipMemsetAsync(cnt, 0, (size_t)N_NODES * 4, stream);
    hipMemsetAsync(cursor, 0, (size_t)N_NODES * 4, stream);

    const int* srcp = ei;
    const int* dstp = ei + N_EDGES;

    int ebl = (N_EDGES + 255) / 256;
    int nbl = (N_NODES + 255) / 256;
    int nb  = (N_NODES + SCAN_B - 1) / SCAN_B;      // 391
    int wbl = (N_NODES * 64 + 255) / 256;           // one wave per node

    k_count<<<ebl, 256, 0, stream>>>(dstp, cnt);
    k_dinv<<<nbl, 256, 0, stream>>>(cnt, dinv);
    k_scan1<<<nb, SCAN_B, 0, stream>>>(cnt, rowptr, bsum);
    k_scan2<<<1, 512, 0, stream>>>(bsum, rowptr, nb);
    k_scan3<<<nb, SCAN_B, 0, stream>>>(rowptr, bsum);
    k_fill<<<ebl, 256, 0, stream>>>(srcp, dstp, rowptr, cursor, colb);

    // layer 1: 320 -> 64
    k_xform1<<<(N_NODES + 3) / 4, 256, 0, stream>>>(x, W1, dinv, u);
    k_agg<<<wbl, 256, 0, stream>>>(u, rowptr, colb, dinv, b1, h);
    // layer 2: 64 -> 64
    k_xform<<<wbl, 256, 0, stream>>>(h, W2, dinv, u);
    k_agg<<<wbl, 256, 0, stream>>>(u, rowptr, colb, dinv, b2, h);
    // layer 3: 64 -> 64, fused with linear head dot
    k_xform<<<wbl, 256, 0, stream>>>(h, W3, dinv, u);
    k_agg_dot<<<wbl, 256, 0, stream>>>(u, rowptr, colb, dinv, b3, Wl, val);

    // pooling: one block per graph, no atomics
    k_gpool<<<N_GRAPHS, 256, 0, stream>>>(val, bat, bl, out);
}

// Round 3
// 809.530 us; speedup vs baseline: 1.8604x; 1.3232x over previous
//
#include <hip/hip_runtime.h>
#include <hip/hip_bf16.h>

#define N_NODES 100000
#define N_EDGES 3200000
#define N_GRAPHS 256
#define D_IN 320
#define D_H 64
#define SCAN_B 256

// ---------------- CSR build ----------------

__global__ void k_count(const int* __restrict__ dst, int* __restrict__ cnt) {
    int e = blockIdx.x * blockDim.x + threadIdx.x;
    if (e < N_EDGES) atomicAdd(&cnt[dst[e]], 1);
}

__global__ void k_dinv(const int* __restrict__ cnt, float* __restrict__ dinv) {
    int i = blockIdx.x * blockDim.x + threadIdx.x;
    if (i < N_NODES) {
        float deg = (float)(cnt[i] + 1);   // +1 self loop
        dinv[i] = 1.0f / sqrtf(deg);
    }
}

__global__ void k_scan1(const int* __restrict__ cnt, int* __restrict__ rowptr,
                        int* __restrict__ bsum) {
    __shared__ int tmp[SCAN_B];
    int idx = blockIdx.x * SCAN_B + threadIdx.x;
    int v = (idx < N_NODES) ? cnt[idx] : 0;
    tmp[threadIdx.x] = v;
    __syncthreads();
    for (int off = 1; off < SCAN_B; off <<= 1) {
        int t = (threadIdx.x >= off) ? tmp[threadIdx.x - off] : 0;
        __syncthreads();
        tmp[threadIdx.x] += t;
        __syncthreads();
    }
    if (idx < N_NODES) rowptr[idx] = tmp[threadIdx.x] - v;   // exclusive
    if (threadIdx.x == SCAN_B - 1) bsum[blockIdx.x] = tmp[threadIdx.x];
}

__global__ void k_scan2(int* __restrict__ bsum, int* __restrict__ rowptr, int nb) {
    __shared__ int tmp[512];
    int v = (threadIdx.x < nb) ? bsum[threadIdx.x] : 0;
    tmp[threadIdx.x] = v;
    __syncthreads();
    for (int off = 1; off < 512; off <<= 1) {
        int t = (threadIdx.x >= off) ? tmp[threadIdx.x - off] : 0;
        __syncthreads();
        tmp[threadIdx.x] += t;
        __syncthreads();
    }
    if (threadIdx.x < nb) bsum[threadIdx.x] = tmp[threadIdx.x] - v;  // exclusive
    if (threadIdx.x == 511) rowptr[N_NODES] = tmp[511];              // total = E
}

__global__ void k_scan3(int* __restrict__ rowptr, const int* __restrict__ bsum) {
    int idx = blockIdx.x * SCAN_B + threadIdx.x;
    if (idx < N_NODES) rowptr[idx] += bsum[blockIdx.x];
}

__global__ void k_fill(const int* __restrict__ src, const int* __restrict__ dst,
                       const int* __restrict__ rowptr, int* __restrict__ cursor,
                       int* __restrict__ col) {
    int e = blockIdx.x * blockDim.x + threadIdx.x;
    if (e < N_EDGES) {
        int d = dst[e];
        int pos = atomicAdd(&cursor[d], 1);
        col[rowptr[d] + pos] = src[e];
    }
}

// ---------------- tiled GEMM transform ----------------
// u[node][f] = (A[node,:] @ W)[f] * dinv[node]
// Block tile: 64 nodes x 64 features, K staged in chunks of 64.
// 256 threads, each computes a 4x4 register tile -> 16 FMA per 2 ds_read_b128.
template<int K>
__global__ __launch_bounds__(256) void k_gemm(const float* __restrict__ A,
                                              const float* __restrict__ W,
                                              const float* __restrict__ dinv,
                                              float* __restrict__ u) {
    __shared__ __align__(16) float xt[64][68];   // transposed x chunk [k][node]
    __shared__ __align__(16) float ws[64][68];   // W chunk [k][feature]
    int t = threadIdx.x;
    int ti = t & 15;        // feature group: features 4*ti .. 4*ti+3
    int tj = t >> 4;        // node group:    nodes    4*tj .. 4*tj+3
    int node0 = blockIdx.x * 64;
    float acc[4][4] = {{0.f}};

    for (int kc = 0; kc < K; kc += 64) {
        if (kc) __syncthreads();    // protect LDS reuse across chunks
#pragma unroll
        for (int p = 0; p < 4; ++p) {
            int m = tj + 16 * p;                       // 0..63
            int node = node0 + m;
            if (node >= N_NODES) node = N_NODES - 1;   // clamp (stores guarded)
            float4 v = *(const float4*)(A + (size_t)node * K + kc + 4 * ti);
            xt[4 * ti + 0][m] = v.x;
            xt[4 * ti + 1][m] = v.y;
            xt[4 * ti + 2][m] = v.z;
            xt[4 * ti + 3][m] = v.w;
            float4 wv = *(const float4*)(W + (size_t)(kc + m) * D_H + 4 * ti);
            *(float4*)&ws[m][4 * ti] = wv;
        }
        __syncthreads();
#pragma unroll 16
        for (int k = 0; k < 64; ++k) {
            float4 xv = *(const float4*)&xt[k][4 * tj];
            float4 wv = *(const float4*)&ws[k][4 * ti];
            float xa[4] = {xv.x, xv.y, xv.z, xv.w};
            float wa[4] = {wv.x, wv.y, wv.z, wv.w};
#pragma unroll
            for (int i = 0; i < 4; ++i)
#pragma unroll
                for (int j = 0; j < 4; ++j)
                    acc[i][j] = fmaf(xa[i], wa[j], acc[i][j]);
        }
    }
#pragma unroll
    for (int i = 0; i < 4; ++i) {
        int node = node0 + 4 * tj + i;
        if (node < N_NODES) {
            float dv = dinv[node];
            float4 o = make_float4(acc[i][0] * dv, acc[i][1] * dv,
                                   acc[i][2] * dv, acc[i][3] * dv);
            *(float4*)(u + (size_t)node * D_H + 4 * ti) = o;
        }
    }
}

// ---------------- aggregation ----------------

__device__ __forceinline__ float agg_gather(const float* __restrict__ u,
                                            const int* __restrict__ col,
                                            int beg, int end, int lane, float acc) {
    int e = beg;
    for (; e + 7 < end; e += 8) {                // 8 independent gathers in flight
        int s0 = col[e],     s1 = col[e + 1], s2 = col[e + 2], s3 = col[e + 3];
        int s4 = col[e + 4], s5 = col[e + 5], s6 = col[e + 6], s7 = col[e + 7];
        float v0 = u[(size_t)s0 * D_H + lane];
        float v1 = u[(size_t)s1 * D_H + lane];
        float v2 = u[(size_t)s2 * D_H + lane];
        float v3 = u[(size_t)s3 * D_H + lane];
        float v4 = u[(size_t)s4 * D_H + lane];
        float v5 = u[(size_t)s5 * D_H + lane];
        float v6 = u[(size_t)s6 * D_H + lane];
        float v7 = u[(size_t)s7 * D_H + lane];
        acc += ((v0 + v1) + (v2 + v3)) + ((v4 + v5) + (v6 + v7));
    }
    for (; e < end; ++e) acc += u[(size_t)col[e] * D_H + lane];
    return acc;
}

// h[i] = relu( dinv[i] * (sum_{src in N(i)} u[src] + u[i]) + b )
__global__ __launch_bounds__(256) void k_agg(const float* __restrict__ u,
                                             const int* __restrict__ rowptr,
                                             const int* __restrict__ col,
                                             const float* __restrict__ dinv,
                                             const float* __restrict__ b,
                                             float* __restrict__ h) {
    int lane = threadIdx.x & 63;
    int node = (blockIdx.x * blockDim.x + threadIdx.x) >> 6;
    if (node >= N_NODES) return;
    float acc = u[(size_t)node * D_H + lane];    // self loop
    acc = agg_gather(u, col, rowptr[node], rowptr[node + 1], lane, acc);
    acc = acc * dinv[node] + b[lane];
    h[(size_t)node * D_H + lane] = fmaxf(acc, 0.0f);
}

// layer 3 fused with the linear head: val[i] = dot(agg_row + b3, Wl)
__global__ __launch_bounds__(256) void k_agg_dot(const float* __restrict__ u,
                                                 const int* __restrict__ rowptr,
                                                 const int* __restrict__ col,
                                                 const float* __restrict__ dinv,
                                                 const float* __restrict__ b,
                                                 const float* __restrict__ Wl,
                                                 float* __restrict__ val) {
    int lane = threadIdx.x & 63;
    int node = (blockIdx.x * blockDim.x + threadIdx.x) >> 6;
    if (node >= N_NODES) return;
    float acc = u[(size_t)node * D_H + lane];    // self loop
    acc = agg_gather(u, col, rowptr[node], rowptr[node + 1], lane, acc);
    acc = acc * dinv[node] + b[lane];
    float v = acc * Wl[lane];
#pragma unroll
    for (int m = 32; m > 0; m >>= 1) v += __shfl_xor(v, m, 64);
    if (lane == 0) val[node] = v;
}

// one block per graph: batch is sorted, binary-search the segment, reduce.
__global__ __launch_bounds__(256) void k_gpool(const float* __restrict__ val,
                                               const int* __restrict__ batch,
                                               const float* __restrict__ bl,
                                               float* __restrict__ out) {
    int g = blockIdx.x;
    int l = 0, r = N_NODES;                      // lower_bound(batch, g)
    while (l < r) { int m = (l + r) >> 1; if (batch[m] < g) l = m + 1; else r = m; }
    int lo = l;
    r = N_NODES;                                 // lower_bound(batch, g+1)
    while (l < r) { int m = (l + r) >> 1; if (batch[m] < g + 1) l = m + 1; else r = m; }
    int hi = l;
    float s = 0.0f;
    for (int i = lo + threadIdx.x; i < hi; i += 256) s += val[i];
#pragma unroll
    for (int m = 32; m > 0; m >>= 1) s += __shfl_xor(s, m, 64);
    __shared__ float red[4];
    int wid = threadIdx.x >> 6, lane = threadIdx.x & 63;
    if (lane == 0) red[wid] = s;
    __syncthreads();
    if (threadIdx.x == 0) {
        float t = red[0] + red[1] + red[2] + red[3];
        out[g] = t / fmaxf((float)(hi - lo), 1.0f) + bl[0];
    }
}

// ---------------- launch ----------------

extern "C" void kernel_launch(void* const* d_in, const int* in_sizes, int n_in,
                              void* d_out, int out_size, void* d_ws, size_t ws_size,
                              hipStream_t stream) {
    const float* x   = (const float*)d_in[0];
    const int*   ei  = (const int*)d_in[1];
    const int*   bat = (const int*)d_in[2];
    const float* W1  = (const float*)d_in[3];
    const float* b1  = (const float*)d_in[4];
    const float* W2  = (const float*)d_in[5];
    const float* b2  = (const float*)d_in[6];
    const float* W3  = (const float*)d_in[7];
    const float* b3  = (const float*)d_in[8];
    const float* Wl  = (const float*)d_in[9];
    const float* bl  = (const float*)d_in[10];
    float* out = (float*)d_out;

    char* p = (char*)d_ws;
    auto alloc = [&](size_t bytes) -> void* {
        void* r = (void*)p;
        p += (bytes + 255) & ~(size_t)255;
        return r;
    };
    int*   cnt    = (int*)alloc((size_t)N_NODES * 4);
    int*   rowptr = (int*)alloc((size_t)(N_NODES + 1) * 4);
    int*   cursor = (int*)alloc((size_t)N_NODES * 4);
    float* dinv   = (float*)alloc((size_t)N_NODES * 4);
    int*   colb   = (int*)alloc((size_t)N_EDGES * 4);
    int*   bsum   = (int*)alloc((size_t)512 * 4);
    float* u      = (float*)alloc((size_t)N_NODES * D_H * 4);
    float* h      = (float*)alloc((size_t)N_NODES * D_H * 4);
    float* val    = (float*)alloc((size_t)N_NODES * 4);

    hipMemsetAsync(cnt, 0, (size_t)N_NODES * 4, stream);
    hipMemsetAsync(cursor, 0, (size_t)N_NODES * 4, stream);

    const int* srcp = ei;
    const int* dstp = ei + N_EDGES;

    int ebl = (N_EDGES + 255) / 256;
    int nbl = (N_NODES + 255) / 256;
    int nb  = (N_NODES + SCAN_B - 1) / SCAN_B;      // 391
    int wbl = (N_NODES * 64 + 255) / 256;           // one wave per node
    int gbl = (N_NODES + 63) / 64;                  // GEMM blocks

    k_count<<<ebl, 256, 0, stream>>>(dstp, cnt);
    k_dinv<<<nbl, 256, 0, stream>>>(cnt, dinv);
    k_scan1<<<nb, SCAN_B, 0, stream>>>(cnt, rowptr, bsum);
    k_scan2<<<1, 512, 0, stream>>>(bsum, rowptr, nb);
    k_scan3<<<nb, SCAN_B, 0, stream>>>(rowptr, bsum);
    k_fill<<<ebl, 256, 0, stream>>>(srcp, dstp, rowptr, cursor, colb);

    // layer 1: 320 -> 64
    k_gemm<D_IN><<<gbl, 256, 0, stream>>>(x, W1, dinv, u);
    k_agg<<<wbl, 256, 0, stream>>>(u, rowptr, colb, dinv, b1, h);
    // layer 2: 64 -> 64
    k_gemm<D_H><<<gbl, 256, 0, stream>>>(h, W2, dinv, u);
    k_agg<<<wbl, 256, 0, stream>>>(u, rowptr, colb, dinv, b2, h);
    // layer 3: 64 -> 64, fused with linear head dot
    k_gemm<D_H><<<gbl, 256, 0, stream>>>(h, W3, dinv, u);
    k_agg_dot<<<wbl, 256, 0, stream>>>(u, rowptr, colb, dinv, b3, Wl, val);

    // pooling: one block per graph, no atomics
    k_gpool<<<N_GRAPHS, 256, 0, stream>>>(val, bat, bl, out);
}